// Round 3
// baseline (398.824 us; speedup 1.0000x reference)
//
#include <hip/hip_runtime.h>

// ProgressiveFocusedAttention, MI355X/gfx950 — fully fused per-window kernel.
// B=4, H=W=128, C=192, 6 heads x 32, window 8x8 (64 tokens), shift 4. 1024 windows.
// Outputs: out (4,128,128,192) fp32 then attn (1024,6,64,64) fp32 (concatenated).
//
// R6: occupancy fix. R5's LDS was 102.4 KB -> 1 block/CU (16.9% occupancy),
// latency-bound (MfmaUtil 4.4%, VALU 16.5%, HBM 14%). xw (25.6 KB) is dead after
// P1's MFMA reads, so alias it onto the q/k region and barrier at P1-mid:
// LDS 76.8 KB -> 2 blocks/CU (12 waves). Phase code identical to passing R5.
//
// MFMA 16x16x32 bf16 layouts (HW-verified across R0-R5):
//   A[m][k]: m = lane&15, k = (lane>>4)*8 + j
//   B[k][n]: n = lane&15, k = (lane>>4)*8 + j
//   D[r][c]: c = lane&15, r = (lane>>4)*4 + reg
//
// LDS map (shorts), 38400 total (76,800 B):
//   [0,24576)      per head h (4096): q [64][32] @+0, k [64][32] @+2048;
//                  after QK^T overlaid by P_h [64][64]
//   [24576,38400)  per head h (2304): vt [32][72] (v^T, LePE'd in place);
//                  after PV overlaid by o_h [64][32]
//   xw [64][200] (12800 shorts) ALIASES [0,12800) — live P0 -> P1-mid barrier only.
//
// Barriers (5): P0-end, P1-mid (xw dead / alias handoff), P1-end (q/k/vt
// cross-lane publish), P4-end (P/vt consumed by P5 cross-lane), P5-end (o_h
// cross-wave publish for proj).

#define SCALE 0.17677669529663687f

typedef __attribute__((ext_vector_type(8))) short short8;
typedef __attribute__((ext_vector_type(4))) float f32x4;

__device__ __forceinline__ unsigned short f2bf(float f) {
    unsigned int u = __float_as_uint(f);
    u = (u + 0x7FFFu + ((u >> 16) & 1u)) >> 16;   // round-to-nearest-even
    return (unsigned short)u;
}
__device__ __forceinline__ float bf2f(unsigned short h) {
    return __uint_as_float(((unsigned int)h) << 16);
}
__device__ __forceinline__ unsigned int pack2(float a, float b) {
    return (unsigned int)f2bf(a) | ((unsigned int)f2bf(b) << 16);
}

// ---------------------------------------------------------------- K0: pack
__global__ __launch_bounds__(256) void k0_pack(const float* __restrict__ qkv_w,
                                               const float* __restrict__ proj_w,
                                               unsigned short* __restrict__ qkvp,
                                               unsigned short* __restrict__ projp) {
    int gid = blockIdx.x * 256 + threadIdx.x;   // grid covers 6*36*64 + 6*12*64 = 18432
    if (gid < 6 * 36 * 64) {
        int lane = gid & 63, tile = gid >> 6;
        int nt = tile % 36, ks = tile / 36;
        int row = ks * 32 + (lane >> 4) * 8, col = nt * 16 + (lane & 15);
        const float* w = qkv_w + (size_t)row * 576 + col;
        uint4 o;
        o.x = pack2(w[0 * 576], w[1 * 576]);
        o.y = pack2(w[2 * 576], w[3 * 576]);
        o.z = pack2(w[4 * 576], w[5 * 576]);
        o.w = pack2(w[6 * 576], w[7 * 576]);
        *(uint4*)(qkvp + (size_t)gid * 8) = o;
    } else {
        int g = gid - 6 * 36 * 64;
        int lane = g & 63, tile = g >> 6;
        int nt = tile % 12, ks = tile / 12;
        int row = ks * 32 + (lane >> 4) * 8, col = nt * 16 + (lane & 15);
        const float* w = proj_w + (size_t)row * 192 + col;
        uint4 o;
        o.x = pack2(w[0 * 192], w[1 * 192]);
        o.y = pack2(w[2 * 192], w[3 * 192]);
        o.z = pack2(w[4 * 192], w[5 * 192]);
        o.w = pack2(w[6 * 192], w[7 * 192]);
        *(uint4*)(projp + (size_t)g * 8) = o;
    }
}

// ---------------------------------------------------------------- fused kernel
#define LDS_QK 0
#define LDS_VT 24576

__global__ __launch_bounds__(384, 3) void k_fused(
    const float* __restrict__ x, const float* __restrict__ prev,
    const float* __restrict__ qkv_b, const float* __restrict__ lepe_w,
    const float* __restrict__ lepe_b, const float* __restrict__ proj_b,
    const unsigned short* __restrict__ qkvp, const unsigned short* __restrict__ projp,
    float* __restrict__ out, float* __restrict__ attn)
{
    __shared__ unsigned short lds[38400];   // 76,800 B -> 2 blocks/CU
    const int wb = blockIdx.x;
    const int b = wb >> 8, wh = (wb >> 4) & 15, wwi = wb & 15;
    const int t = threadIdx.x;
    const int lane = t & 63, h = t >> 6, quad = lane >> 4, l16 = lane & 15;
    const f32x4 fz = {0.f, 0.f, 0.f, 0.f};

    // ---- P0: shifted-window load, fp32 -> bf16, fully coalesced.
    // xw [64][200] aliases lds[0..12800): live only until the P1-mid barrier.
#pragma unroll
    for (int kk = 0; kk < 8; ++kk) {
        int f = kk * 384 + t;                 // float4 id within window, 0..3071
        int token = f / 48, c4 = f - token * 48;
        int i = token >> 3, j = token & 7;
        int hh = (wh * 8 + i + 4) & 127, wp = (wwi * 8 + j + 4) & 127;
        const float4 v4 = *(const float4*)(x + ((size_t)((b * 128 + hh) * 128 + wp)) * 192 + c4 * 4);
        unsigned int* d = (unsigned int*)&lds[token * 200 + c4 * 4];
        d[0] = pack2(v4.x, v4.y);
        d[1] = pack2(v4.z, v4.w);
    }
    __syncthreads();

    // column-tile ids for this head: q:{2h,2h+1} k:{12+2h,13+2h} v:{24+2h,25+2h}
    const int ntg[6] = {2 * h, 2 * h + 1, 12 + 2 * h, 13 + 2 * h, 24 + 2 * h, 25 + 2 * h};

    unsigned short* qh  = &lds[LDS_QK + h * 4096];
    unsigned short* kh  = qh + 2048;
    unsigned short* vth = &lds[LDS_VT + h * 2304];

    // ---- P1: qkv_h = xw(64x192) @ W[:, head-h tiles]; 144 MFMA / wave
    {
        f32x4 acc[6][4];
#pragma unroll
        for (int j = 0; j < 6; ++j)
#pragma unroll
            for (int m = 0; m < 4; ++m) acc[j][m] = fz;

#pragma unroll
        for (int ks = 0; ks < 6; ++ks) {
            short8 a[4];
#pragma unroll
            for (int m = 0; m < 4; ++m)
                a[m] = *(const short8*)&lds[(m * 16 + l16) * 200 + ks * 32 + quad * 8];
#pragma unroll
            for (int j = 0; j < 6; ++j) {
                short8 bf = *(const short8*)(qkvp + (((size_t)(ks * 36 + ntg[j]) * 64 + lane) << 3));
#pragma unroll
                for (int m = 0; m < 4; ++m)
                    acc[j][m] = __builtin_amdgcn_mfma_f32_16x16x32_bf16(a[m], bf, acc[j][m], 0, 0, 0);
            }
        }
        __syncthreads();   // P1-mid: all xw reads done; q/k/vt may now overwrite it

        // epilogue: +bias -> bf16 -> q/k strips [token][ch], v -> vt [ch][token]
#pragma unroll
        for (int j = 0; j < 6; ++j) {
            float bias = qkv_b[ntg[j] * 16 + l16];
#pragma unroll
            for (int m = 0; m < 4; ++m) {
#pragma unroll
                for (int r = 0; r < 4; ++r) {
                    int token = m * 16 + quad * 4 + r;
                    unsigned short bv = f2bf(acc[j][m][r] + bias);
                    if (j < 2)      qh[token * 32 + j * 16 + l16] = bv;
                    else if (j < 4) kh[token * 32 + (j - 2) * 16 + l16] = bv;
                    else            vth[((j - 4) * 16 + l16) * 72 + token] = bv;
                }
            }
        }
    }
    __syncthreads();   // P1-end: q/k/vt published (cross-lane consumers below)

    // ---- P2: LePE 3x3 depthwise conv (zero-pad inside window) + residual, in place.
    // Channels independent; all 9 reads of channel ci precede its write.
    {
        const int ti = lane >> 3, tj = lane & 7;
        for (int ci = 0; ci < 32; ++ci) {
            int c = h * 32 + ci;
            const unsigned short* vr = vth + ci * 72;
            float sum = bf2f(vr[lane]) + lepe_b[c];
#pragma unroll
            for (int di = -1; di <= 1; ++di)
#pragma unroll
                for (int dj = -1; dj <= 1; ++dj) {
                    int ii = ti + di, jj = tj + dj;
                    if (ii >= 0 && ii < 8 && jj >= 0 && jj < 8)
                        sum += bf2f(vr[ii * 8 + jj]) * lepe_w[((di + 1) * 3 + (dj + 1)) * 192 + c];
                }
            vth[ci * 72 + lane] = f2bf(sum);
        }
    }
    // no barrier: P3 touches only q/k (published at P1-end); vt next consumed in P5
    // after the P4-end barrier.

    // ---- P3: QK^T (whole head per wave: 4x4 tiles, K=32 in one MFMA step)
    f32x4 s4[4][4];
    {
        short8 aq[4];
#pragma unroll
        for (int m = 0; m < 4; ++m)
            aq[m] = *(const short8*)(qh + (m * 16 + l16) * 32 + quad * 8);
#pragma unroll
        for (int nt = 0; nt < 4; ++nt) {
            short8 bk = *(const short8*)(kh + (nt * 16 + l16) * 32 + quad * 8);
#pragma unroll
            for (int m = 0; m < 4; ++m)
                s4[m][nt] = __builtin_amdgcn_mfma_f32_16x16x32_bf16(aq[m], bk, fz, 0, 0, 0);
        }
    }

    // ---- P4: gate with prev, softmax, write attn (fp32), stage P (bf16) over q+k.
    const float* pvm = prev + (((size_t)wb * 6 + h) << 12);
    float* aom = attn + (((size_t)wb * 6 + h) << 12);
    unsigned short* Ph = qh;                      // [64][64] overlay
#pragma unroll
    for (int m = 0; m < 4; ++m) {
        float e[4][4], inv[4];
#pragma unroll
        for (int r = 0; r < 4; ++r) {
            int row = m * 16 + quad * 4 + r;
            float ps = 0.f;
#pragma unroll
            for (int nt = 0; nt < 4; ++nt) {
                float sg = s4[m][nt][r] * SCALE * pvm[row * 64 + nt * 16 + l16];
                float ev = __expf(sg);
                e[r][nt] = ev; ps += ev;
            }
            ps += __shfl_xor(ps, 1); ps += __shfl_xor(ps, 2);
            ps += __shfl_xor(ps, 4); ps += __shfl_xor(ps, 8);
            inv[r] = 1.0f / ps;
        }
#pragma unroll
        for (int r = 0; r < 4; ++r) {
            int row = m * 16 + quad * 4 + r;
#pragma unroll
            for (int nt = 0; nt < 4; ++nt) {
                float av = e[r][nt] * inv[r];
                aom[row * 64 + nt * 16 + l16] = av;
                Ph[row * 64 + nt * 16 + l16] = f2bf(av);
            }
        }
    }
    __syncthreads();   // P4-end: P (and P2's vt) published for cross-lane P5 reads

    // ---- P5: PV: out_h(64x32) = P(64x64) @ v_h(64x32); stage o_h over dead vt strip
    {
        f32x4 o2[4][2];
#pragma unroll
        for (int m = 0; m < 4; ++m) { o2[m][0] = fz; o2[m][1] = fz; }
#pragma unroll
        for (int ks = 0; ks < 2; ++ks) {
            short8 ap[4];
#pragma unroll
            for (int m = 0; m < 4; ++m)
                ap[m] = *(const short8*)(Ph + (m * 16 + l16) * 64 + ks * 32 + quad * 8);
#pragma unroll
            for (int n2 = 0; n2 < 2; ++n2) {
                short8 bv = *(const short8*)(vth + (n2 * 16 + l16) * 72 + ks * 32 + quad * 8);
#pragma unroll
                for (int m = 0; m < 4; ++m)
                    o2[m][n2] = __builtin_amdgcn_mfma_f32_16x16x32_bf16(ap[m], bv, o2[m][n2], 0, 0, 0);
            }
        }
        unsigned short* oh = vth;                 // [64][32] overlay
#pragma unroll
        for (int m = 0; m < 4; ++m)
#pragma unroll
            for (int n2 = 0; n2 < 2; ++n2)
#pragma unroll
                for (int r = 0; r < 4; ++r)
                    oh[(m * 16 + quad * 4 + r) * 32 + n2 * 16 + l16] = f2bf(o2[m][n2][r]);
    }
    __syncthreads();   // P5-end: all heads' o_h staged (cross-wave proj reads)

    // ---- P6: proj: out(64x192) = o(64x192) @ proj_w; wave h owns 2 N-tiles.
    {
        f32x4 p3[2][4];
#pragma unroll
        for (int n = 0; n < 2; ++n)
#pragma unroll
            for (int m = 0; m < 4; ++m) p3[n][m] = fz;

#pragma unroll
        for (int ks = 0; ks < 6; ++ks) {
            const unsigned short* ob = &lds[LDS_VT + ks * 2304];   // head-ks o block [64][32]
            short8 a3[4];
#pragma unroll
            for (int m = 0; m < 4; ++m)
                a3[m] = *(const short8*)(ob + (m * 16 + l16) * 32 + quad * 8);
#pragma unroll
            for (int n = 0; n < 2; ++n) {
                short8 bf = *(const short8*)(projp + (((size_t)(ks * 12 + h * 2 + n) * 64 + lane) << 3));
#pragma unroll
                for (int m = 0; m < 4; ++m)
                    p3[n][m] = __builtin_amdgcn_mfma_f32_16x16x32_bf16(a3[m], bf, p3[n][m], 0, 0, 0);
            }
        }
#pragma unroll
        for (int n = 0; n < 2; ++n) {
            int col = (h * 2 + n) * 16 + l16;
            float bias = proj_b[col];
#pragma unroll
            for (int m = 0; m < 4; ++m)
#pragma unroll
                for (int r = 0; r < 4; ++r) {
                    int token = m * 16 + quad * 4 + r;
                    int i = token >> 3, j = token & 7;
                    int hh = (wh * 8 + i + 4) & 127, wp = (wwi * 8 + j + 4) & 127;
                    out[((size_t)((b * 128 + hh) * 128 + wp)) * 192 + col] = p3[n][m][r] + bias;
                }
        }
    }
}

// ---------------------------------------------------------------- launch
extern "C" void kernel_launch(void* const* d_in, const int* in_sizes, int n_in,
                              void* d_out, int out_size, void* d_ws, size_t ws_size,
                              hipStream_t stream) {
    const float* x      = (const float*)d_in[0];
    const float* prev   = (const float*)d_in[1];
    const float* qkv_w  = (const float*)d_in[2];
    const float* qkv_b  = (const float*)d_in[3];
    const float* proj_w = (const float*)d_in[4];
    const float* proj_b = (const float*)d_in[5];
    const float* lepe_w = (const float*)d_in[6];
    const float* lepe_b = (const float*)d_in[7];

    float* out  = (float*)d_out;
    float* attn = out + (size_t)4 * 128 * 128 * 192;   // second output, concatenated

    char* ws = (char*)d_ws;
    const size_t SZ_QKVP = 192 * 576 * 2;              // 221184
    unsigned short* qkvp  = (unsigned short*)(ws);
    unsigned short* projp = (unsigned short*)(ws + SZ_QKVP);

    k0_pack<<<72, 256, 0, stream>>>(qkv_w, proj_w, qkvp, projp);
    k_fused<<<1024, 384, 0, stream>>>(x, prev, qkv_b, lepe_w, lepe_b, proj_b,
                                      qkvp, projp, out, attn);
}

// Round 5
// 395.965 us; speedup vs baseline: 1.0072x; 1.0072x over previous
//
#include <hip/hip_runtime.h>

// ProgressiveFocusedAttention, MI355X/gfx950 — fully fused per-window kernel.
// B=4, H=W=128, C=192, 6 heads x 32, window 8x8 (64 tokens), shift 4. 1024 windows.
// Outputs: out (4,128,128,192) fp32 then attn (1024,6,64,64) fp32 (concatenated).
//
// R8: R7's 52KB region scheme (2 blocks/CU under the ~128KB-usable pool implied by
// R6's measurement: 76.8KB stayed at 1 block) + R5/R6's HW-proven pitches, NO XOR
// swizzles (wave64 ds_read_b128 already sits at the 8-cycle bank floor with pitch
// 32/72/200), 3 barriers. v held in 32 VGPRs across QK^T (R7-validated dataflow).
//
// MFMA 16x16x32 bf16 layouts (HW-verified across R0-R7):
//   A[m][k]: m = lane&15, k = (lane>>4)*8 + j
//   B[k][n]: n = lane&15, k = (lane>>4)*8 + j
//   D[r][c]: c = lane&15, r = (lane>>4)*4 + reg
//
// LDS map (shorts), 26112 total (52,224 B). Rh = lds + h*4352:
//   P0-P1:      xw [64][200] = lds[0:12800]  (aliases heads 0-2 regions; dead at P1-mid)
//   P1epi-QK^T: q [64][32] @ Rh+0, k [64][32] @ Rh+2048
//   post-QK^T:  vt [32][72] @ Rh+0 (over q; tail overlaps dead k head)
//   P5:         P-half [64][32] @ Rh+2304; o [64][32] @ Rh+2304 (over P-half)
// Barriers (3): P0-end, P1-mid (xw dead), P5-end (o cross-wave publish).
// Everything between P1-mid and P5-end is wave-private (R7-validated).

#define SCALE 0.17677669529663687f

typedef __attribute__((ext_vector_type(8))) short short8;
typedef __attribute__((ext_vector_type(4))) float f32x4;

__device__ __forceinline__ unsigned short f2bf(float f) {
    unsigned int u = __float_as_uint(f);
    u = (u + 0x7FFFu + ((u >> 16) & 1u)) >> 16;   // round-to-nearest-even
    return (unsigned short)u;
}
__device__ __forceinline__ float bf2f(unsigned short h) {
    return __uint_as_float(((unsigned int)h) << 16);
}
__device__ __forceinline__ unsigned int pack2(float a, float b) {
    return (unsigned int)f2bf(a) | ((unsigned int)f2bf(b) << 16);
}

// ---------------------------------------------------------------- K0: pack
__global__ __launch_bounds__(256) void k0_pack(const float* __restrict__ qkv_w,
                                               const float* __restrict__ proj_w,
                                               unsigned short* __restrict__ qkvp,
                                               unsigned short* __restrict__ projp) {
    int gid = blockIdx.x * 256 + threadIdx.x;   // grid covers 6*36*64 + 6*12*64 = 18432
    if (gid < 6 * 36 * 64) {
        int lane = gid & 63, tile = gid >> 6;
        int nt = tile % 36, ks = tile / 36;
        int row = ks * 32 + (lane >> 4) * 8, col = nt * 16 + (lane & 15);
        const float* w = qkv_w + (size_t)row * 576 + col;
        uint4 o;
        o.x = pack2(w[0 * 576], w[1 * 576]);
        o.y = pack2(w[2 * 576], w[3 * 576]);
        o.z = pack2(w[4 * 576], w[5 * 576]);
        o.w = pack2(w[6 * 576], w[7 * 576]);
        *(uint4*)(qkvp + (size_t)gid * 8) = o;
    } else {
        int g = gid - 6 * 36 * 64;
        int lane = g & 63, tile = g >> 6;
        int nt = tile % 12, ks = tile / 12;
        int row = ks * 32 + (lane >> 4) * 8, col = nt * 16 + (lane & 15);
        const float* w = proj_w + (size_t)row * 192 + col;
        uint4 o;
        o.x = pack2(w[0 * 192], w[1 * 192]);
        o.y = pack2(w[2 * 192], w[3 * 192]);
        o.z = pack2(w[4 * 192], w[5 * 192]);
        o.w = pack2(w[6 * 192], w[7 * 192]);
        *(uint4*)(projp + (size_t)g * 8) = o;
    }
}

// ---------------------------------------------------------------- fused kernel
#define RH 4352    // per-head region pitch (shorts)
#define KO 2048    // k offset within region
#define PO 2304    // P-half / o offset within region

__global__ __launch_bounds__(384, 3) void k_fused(
    const float* __restrict__ x, const float* __restrict__ prev,
    const float* __restrict__ qkv_b, const float* __restrict__ lepe_w,
    const float* __restrict__ lepe_b, const float* __restrict__ proj_b,
    const unsigned short* __restrict__ qkvp, const unsigned short* __restrict__ projp,
    float* __restrict__ out, float* __restrict__ attn)
{
    __shared__ unsigned short lds[26112];   // 52,224 B -> 2 blocks/CU
    const int wb = blockIdx.x;
    const int b = wb >> 8, wh = (wb >> 4) & 15, wwi = wb & 15;
    const int t = threadIdx.x;
    const int lane = t & 63, h = t >> 6, quad = lane >> 4, l16 = lane & 15;
    const f32x4 fz = {0.f, 0.f, 0.f, 0.f};

    // ---- P0: shifted-window load, fp32 -> bf16, coalesced; xw [64][200] @ lds[0]
#pragma unroll
    for (int kk = 0; kk < 8; ++kk) {
        int f = kk * 384 + t;                 // float4 id within window, 0..3071
        int token = f / 48, c4 = f - token * 48;
        int i = token >> 3, j = token & 7;
        int hh = (wh * 8 + i + 4) & 127, wp = (wwi * 8 + j + 4) & 127;
        const float4 v4 = *(const float4*)(x + ((size_t)((b * 128 + hh) * 128 + wp)) * 192 + c4 * 4);
        unsigned int* d = (unsigned int*)&lds[token * 200 + c4 * 4];
        d[0] = pack2(v4.x, v4.y);
        d[1] = pack2(v4.z, v4.w);
    }
    __syncthreads();   // P0-end: xw published

    // column-tile ids for this head: q:{2h,2h+1} k:{12+2h,13+2h} v:{24+2h,25+2h}
    const int ntg[6] = {2 * h, 2 * h + 1, 12 + 2 * h, 13 + 2 * h, 24 + 2 * h, 25 + 2 * h};
    unsigned short* qh  = &lds[h * RH];
    unsigned short* kh  = qh + KO;
    unsigned short* vth = qh;          // vt [32][72] overlays q (+ dead k head) post-QK^T
    unsigned short* Pf  = qh + PO;     // P-half / o region

    // ---- P1: qkv_h = xw(64x192) @ W[:, head-h tiles]; 144 MFMA / wave
    f32x4 acc[6][4];
#pragma unroll
    for (int j = 0; j < 6; ++j)
#pragma unroll
        for (int m = 0; m < 4; ++m) acc[j][m] = fz;

#pragma unroll
    for (int ks = 0; ks < 6; ++ks) {
        short8 a[4];
#pragma unroll
        for (int m = 0; m < 4; ++m)
            a[m] = *(const short8*)&lds[(m * 16 + l16) * 200 + ks * 32 + quad * 8];
#pragma unroll
        for (int j = 0; j < 6; ++j) {
            short8 bf = *(const short8*)(qkvp + (((size_t)(ks * 36 + ntg[j]) * 64 + lane) << 3));
#pragma unroll
            for (int m = 0; m < 4; ++m)
                acc[j][m] = __builtin_amdgcn_mfma_f32_16x16x32_bf16(a[m], bf, acc[j][m], 0, 0, 0);
        }
    }
    __syncthreads();   // P1-mid: all xw reads done; q/k may overwrite it

    // epilogue: q (j=0,1), k (j=2,3) -> [64][32] strips; v accs (j=4,5) stay in regs
#pragma unroll
    for (int j = 0; j < 4; ++j) {
        float bias = qkv_b[ntg[j] * 16 + l16];
        unsigned short* base = (j < 2) ? qh : kh;
#pragma unroll
        for (int m = 0; m < 4; ++m) {
#pragma unroll
            for (int r = 0; r < 4; ++r) {
                int token = m * 16 + quad * 4 + r;
                base[token * 32 + (j & 1) * 16 + l16] = f2bf(acc[j][m][r] + bias);
            }
        }
    }
    // No barrier: everything until P5-end is wave-private (same-wave LDS forwarding
    // validated by R6/R7 passing runs).

    // ---- P3: QK^T (whole head per wave: 4x4 tiles, K=32 in one MFMA step)
    f32x4 s4[4][4];
    {
        short8 aq[4];
#pragma unroll
        for (int m = 0; m < 4; ++m)
            aq[m] = *(const short8*)(qh + (m * 16 + l16) * 32 + quad * 8);
#pragma unroll
        for (int nt = 0; nt < 4; ++nt) {
            short8 bk = *(const short8*)(kh + (nt * 16 + l16) * 32 + quad * 8);
#pragma unroll
            for (int m = 0; m < 4; ++m)
                s4[m][nt] = __builtin_amdgcn_mfma_f32_16x16x32_bf16(aq[m], bk, fz, 0, 0, 0);
        }
    }

    // ---- vt write over dead q strip: v = acc[4],acc[5] + bias, layout [ch][token]
#pragma unroll
    for (int j = 4; j < 6; ++j) {
        float bias = qkv_b[ntg[j] * 16 + l16];
        int ch = (j - 4) * 16 + l16;
#pragma unroll
        for (int m = 0; m < 4; ++m) {
#pragma unroll
            for (int r = 0; r < 4; ++r) {
                int token = m * 16 + quad * 4 + r;
                vth[ch * 72 + token] = f2bf(acc[j][m][r] + bias);
            }
        }
    }

    // ---- P2: LePE 3x3 depthwise conv (zero-pad inside window) + residual, in place.
    // Channels independent; all 9 reads of channel ci precede its write (proven).
    {
        const int ti = lane >> 3, tj = lane & 7;
        for (int ci = 0; ci < 32; ++ci) {
            int c = h * 32 + ci;
            const unsigned short* vr = vth + ci * 72;
            float sum = bf2f(vr[lane]) + lepe_b[c];
#pragma unroll
            for (int di = -1; di <= 1; ++di)
#pragma unroll
                for (int dj = -1; dj <= 1; ++dj) {
                    int ii = ti + di, jj = tj + dj;
                    if (ii >= 0 && ii < 8 && jj >= 0 && jj < 8)
                        sum += bf2f(vr[ii * 8 + jj]) * lepe_w[((di + 1) * 3 + (dj + 1)) * 192 + c];
                }
            vth[ci * 72 + lane] = f2bf(sum);
        }
    }

    // ---- P4: gate with prev, softmax (fp32, |scores| small: no max-sub), write attn;
    // keep P values in s4 for the two-half PV.
    const float* pvm = prev + (((size_t)wb * 6 + h) << 12);
    float* aom = attn + (((size_t)wb * 6 + h) << 12);
#pragma unroll
    for (int m = 0; m < 4; ++m) {
        float inv[4];
#pragma unroll
        for (int r = 0; r < 4; ++r) {
            int row = m * 16 + quad * 4 + r;
            float ps = 0.f;
#pragma unroll
            for (int nt = 0; nt < 4; ++nt) {
                float sg = s4[m][nt][r] * SCALE * pvm[row * 64 + nt * 16 + l16];
                float ev = __expf(sg);
                s4[m][nt][r] = ev; ps += ev;
            }
            ps += __shfl_xor(ps, 1); ps += __shfl_xor(ps, 2);
            ps += __shfl_xor(ps, 4); ps += __shfl_xor(ps, 8);
            inv[r] = 1.0f / ps;
        }
#pragma unroll
        for (int r = 0; r < 4; ++r) {
            int row = m * 16 + quad * 4 + r;
#pragma unroll
            for (int nt = 0; nt < 4; ++nt) {
                float av = s4[m][nt][r] * inv[r];
                s4[m][nt][r] = av;
                aom[row * 64 + nt * 16 + l16] = av;
            }
        }
    }

    // ---- P5: PV in two K=32 halves; P-half [64][32] @ Pf, consumed immediately
    {
        f32x4 o2[4][2];
#pragma unroll
        for (int m = 0; m < 4; ++m) { o2[m][0] = fz; o2[m][1] = fz; }
#pragma unroll
        for (int half = 0; half < 2; ++half) {
            // store this half of P (keys half*32 .. half*32+31)
#pragma unroll
            for (int m = 0; m < 4; ++m)
#pragma unroll
                for (int nt2 = 0; nt2 < 2; ++nt2)
#pragma unroll
                    for (int r = 0; r < 4; ++r) {
                        int row = m * 16 + quad * 4 + r;
                        Pf[row * 32 + nt2 * 16 + l16] = f2bf(s4[m][half * 2 + nt2][r]);
                    }
            // consume: O += P_half @ V_half
            short8 ap[4];
#pragma unroll
            for (int m = 0; m < 4; ++m)
                ap[m] = *(const short8*)(Pf + (m * 16 + l16) * 32 + quad * 8);
#pragma unroll
            for (int n2 = 0; n2 < 2; ++n2) {
                short8 bv = *(const short8*)(vth + (n2 * 16 + l16) * 72 + half * 32 + quad * 8);
#pragma unroll
                for (int m = 0; m < 4; ++m)
                    o2[m][n2] = __builtin_amdgcn_mfma_f32_16x16x32_bf16(ap[m], bv, o2[m][n2], 0, 0, 0);
            }
        }
        // o_h [64][32] over the consumed P-half region
#pragma unroll
        for (int m = 0; m < 4; ++m)
#pragma unroll
            for (int n2 = 0; n2 < 2; ++n2)
#pragma unroll
                for (int r = 0; r < 4; ++r) {
                    int token = m * 16 + quad * 4 + r;
                    Pf[token * 32 + n2 * 16 + l16] = f2bf(o2[m][n2][r]);
                }
    }
    __syncthreads();   // P5-end: all heads' o_h staged (cross-wave proj reads)

    // ---- P6: proj: out(64x192) = o(64x192) @ proj_w; wave h owns 2 N-tiles.
    {
        f32x4 p3[2][4];
#pragma unroll
        for (int n = 0; n < 2; ++n)
#pragma unroll
            for (int m = 0; m < 4; ++m) p3[n][m] = fz;

#pragma unroll
        for (int ks = 0; ks < 6; ++ks) {
            const unsigned short* ob = &lds[ks * RH + PO];   // head-ks o block [64][32]
            short8 a3[4];
#pragma unroll
            for (int m = 0; m < 4; ++m)
                a3[m] = *(const short8*)(ob + (m * 16 + l16) * 32 + quad * 8);
#pragma unroll
            for (int n = 0; n < 2; ++n) {
                short8 bf = *(const short8*)(projp + (((size_t)(ks * 12 + h * 2 + n) * 64 + lane) << 3));
#pragma unroll
                for (int m = 0; m < 4; ++m)
                    p3[n][m] = __builtin_amdgcn_mfma_f32_16x16x32_bf16(a3[m], bf, p3[n][m], 0, 0, 0);
            }
        }
#pragma unroll
        for (int n = 0; n < 2; ++n) {
            int col = (h * 2 + n) * 16 + l16;
            float bias = proj_b[col];
#pragma unroll
            for (int m = 0; m < 4; ++m)
#pragma unroll
                for (int r = 0; r < 4; ++r) {
                    int token = m * 16 + quad * 4 + r;
                    int i = token >> 3, j = token & 7;
                    int hh = (wh * 8 + i + 4) & 127, wp = (wwi * 8 + j + 4) & 127;
                    out[((size_t)((b * 128 + hh) * 128 + wp)) * 192 + col] = p3[n][m][r] + bias;
                }
        }
    }
}

// ---------------------------------------------------------------- launch
extern "C" void kernel_launch(void* const* d_in, const int* in_sizes, int n_in,
                              void* d_out, int out_size, void* d_ws, size_t ws_size,
                              hipStream_t stream) {
    const float* x      = (const float*)d_in[0];
    const float* prev   = (const float*)d_in[1];
    const float* qkv_w  = (const float*)d_in[2];
    const float* qkv_b  = (const float*)d_in[3];
    const float* proj_w = (const float*)d_in[4];
    const float* proj_b = (const float*)d_in[5];
    const float* lepe_w = (const float*)d_in[6];
    const float* lepe_b = (const float*)d_in[7];

    float* out  = (float*)d_out;
    float* attn = out + (size_t)4 * 128 * 128 * 192;   // second output, concatenated

    char* ws = (char*)d_ws;
    const size_t SZ_QKVP = 192 * 576 * 2;              // 221184
    unsigned short* qkvp  = (unsigned short*)(ws);
    unsigned short* projp = (unsigned short*)(ws + SZ_QKVP);

    k0_pack<<<72, 256, 0, stream>>>(qkv_w, proj_w, qkvp, projp);
    k_fused<<<1024, 384, 0, stream>>>(x, prev, qkv_b, lepe_w, lepe_b, proj_b,
                                      qkvp, projp, out, attn);
}